// Round 5
// baseline (2832.894 us; speedup 1.0000x reference)
//
#include <hip/hip_runtime.h>
#include <hip/hip_bf16.h>

// Problem constants
constexpr int Bs = 512;   // batch
constexpr int Ss = 256;   // seq len
constexpr int Is = 32;    // input dim
constexpr int Hs = 256;   // hidden
constexpr int Os = 24;    // output dim
constexpr int MB = 16;    // batches per block
constexpr int NBLK = Bs / MB;  // 32 blocks
constexpr int NTH = 256;       // 4 waves, 1 wave/SIMD -> 512 unified regs/wave

typedef __attribute__((ext_vector_type(8))) short short8;
typedef __attribute__((ext_vector_type(4))) float f32x4;

#define DEV static __device__ __forceinline__

DEV short f2bf(float f) {
  __hip_bfloat16 h = __float2bfloat16(f);
  short s;
  __builtin_memcpy(&s, &h, 2);
  return s;
}

DEV float frcp(float x) { return __builtin_amdgcn_rcpf(x); }

DEV float tanh_fast(float x) {
  x = fminf(fmaxf(x, -15.f), 15.f);
  float u = __expf(2.f * x);
  return (u - 1.f) * frcp(u + 1.f);
}

DEV short8 ldg8(const short* p) { return *reinterpret_cast<const short8*>(p); }

DEV float xvf(uint2 v, int r) {
  unsigned wd = (r & 2) ? v.y : v.x;
  unsigned bits = ((r & 1) ? (wd >> 16) : (wd & 0xffffu)) << 16;
  float f;
  __builtin_memcpy(&f, &bits, 4);
  return f;
}

// ---------------- prep kernels (layouts identical to verified R3) ----------------
// Frag key q = hg*4 + g, hg = hidden/16 in [0,16), g = gate (0=i,1=f,2=z,3=o).
// wst[(q*8+kt)*512 + l*8 + j] = Whr[gr][k], gr = g*256 + hg*16 + (l&15),
//   k = kt*32 + (l>>4)*8 + j, value = W[gr][256+k] + R[gr][k]
__global__ void prep_wstream(const float* __restrict__ W, const float* __restrict__ R,
                             short* __restrict__ wst) {
  int tid = blockIdx.x * 256 + threadIdx.x;  // 262144 total
  int j  = tid & 7;
  int l  = (tid >> 3) & 63;
  int kt = (tid >> 9) & 7;
  int q  = tid >> 12;          // 0..63
  int n = l & 15, kg = (l >> 4) & 3;
  int g = q & 3, hg = q >> 2;
  int gr = g * 256 + hg * 16 + n;
  int k  = kt * 32 + kg * 8 + j;
  float v = W[gr * 512 + 256 + k] + R[gr * 256 + k];
  wst[tid] = f2bf(v);
}

// Weff = Wx @ W_in (1024 x 32) as B-frags: weff[q*512 + l*8 + j]
__global__ void prep_weff(const float* __restrict__ W, const float* __restrict__ W_in,
                          short* __restrict__ weff) {
  int tid = blockIdx.x * 256 + threadIdx.x;  // 32768 total
  int j  = tid & 7;
  int l  = (tid >> 3) & 63;
  int q  = tid >> 9;           // 0..63
  int n = l & 15, kg = (l >> 4) & 3;
  int g = q & 3, hg = q >> 2;
  int gr = g * 256 + hg * 16 + n;
  int i  = kg * 8 + j;
  float acc = 0.f;
  for (int h = 0; h < Hs; ++h) acc += W[gr * 512 + h] * W_in[h * 32 + i];
  weff[tid] = f2bf(acc);
}

// bfrag[q*64 + l] = b[gr] + dot(W[gr, 0:256], b_in)
__global__ void prep_bfrag(const float* __restrict__ W, const float* __restrict__ b,
                           const float* __restrict__ b_in, float* __restrict__ bf) {
  int tid = blockIdx.x * 256 + threadIdx.x;  // 4096
  int l = tid & 63, q = tid >> 6;
  int g = q & 3, hg = q >> 2;
  int gr = g * 256 + hg * 16 + (l & 15);
  float a = b[gr];
  for (int h = 0; h < Hs; ++h) a += W[gr * 512 + h] * b_in[h];
  bf[tid] = a;
}

// ---------------- xp chunk GEMM (wave-private: wave w owns q in [w*16, w*16+16)) ----
// xps[(tt*64 + q)*256 + l*4 + r] : packed bf16, (batch=(l>>4)*4+r, col l&15 of q)
template <int TC>
DEV void chunk_gemm4(const float* __restrict__ x, const short* __restrict__ weffF,
                     const float* __restrict__ bfrag, short* __restrict__ xps,
                     int b0, int w, int l, int t0) {
  const int l15 = l & 15, lhi = l >> 4;
  short8 xa[TC];
  const float* px0 = x + (size_t)(b0 + l15) * (Ss * Is) + lhi * 8;
#pragma unroll
  for (int tt = 0; tt < TC; ++tt) {
    const float* px = px0 + (size_t)(t0 + tt) * Is;
    f32x4 a0 = *(const f32x4*)px;
    f32x4 a1 = *(const f32x4*)(px + 4);
#pragma unroll
    for (int j = 0; j < 4; ++j) { xa[tt][j] = f2bf(a0[j]); xa[tt][4 + j] = f2bf(a1[j]); }
  }
#pragma unroll
  for (int nt = 0; nt < 16; ++nt) {
    int q = w * 16 + nt;
    short8 wf = ldg8(weffF + (size_t)q * 512 + l * 8);
    float bv = bfrag[q * 64 + l];
#pragma unroll
    for (int tt = 0; tt < TC; ++tt) {
      f32x4 c = {bv, bv, bv, bv};
      c = __builtin_amdgcn_mfma_f32_16x16x32_bf16(xa[tt], wf, c, 0, 0, 0);
      unsigned lo = ((unsigned)(unsigned short)f2bf(c[1]) << 16) | (unsigned short)f2bf(c[0]);
      unsigned hi = ((unsigned)(unsigned short)f2bf(c[3]) << 16) | (unsigned short)f2bf(c[2]);
      uint2 v; v.x = lo; v.y = hi;
      *reinterpret_cast<uint2*>(xps + (size_t)tt * 16384 + (size_t)q * 256 + l * 4) = v;
    }
  }
}

// ---------------- main recurrent kernel ----------------
// 32 blocks x 4 waves (256 thr). Wave w owns hidden [w*64, w*64+64) x 4 gates
// = 16 N-frags (ql = hh*4+g). Whr residency: kt0-5 in VGPR/AGPR (96 frags =
// 384 regs), kt6-7 in LDS (32 frags/wave = 128 KB). h via LDS dbuf (16 KB).
// 1 wave/SIMD -> 512 unified regs/wave; one barrier per step.
template <int TC>
__global__ __launch_bounds__(NTH, 1) void slstm_main(
    const float* __restrict__ x,
    const short* __restrict__ Wst,
    const short* __restrict__ WeffF,
    const float* __restrict__ Bfrag,
    const float* __restrict__ Wout,
    const float* __restrict__ bout,
    short* __restrict__ xp,
    float* __restrict__ out)
{
  extern __shared__ char smem[];
  short* hbuf = reinterpret_cast<short*>(smem);            // 2 * 4096 shorts = 16 KB
  short* wlds = reinterpret_cast<short*>(smem + 16384);    // 4*32*512 shorts = 128 KB

  const int tid = threadIdx.x;
  const int w   = tid >> 6;   // 0..3
  const int l   = tid & 63;
  const int lg  = l >> 4;
  const int n16 = l & 15;
  const int bb  = blockIdx.x;
  const int b0  = bb * MB;

  const short* wsb = Wst + (size_t)(w * 16 * 8) * 512 + l * 8;  // frag(ql,kt) at +(ql*8+kt)*512
  const f32x4 zero4 = {0.f, 0.f, 0.f, 0.f};

  // persistent weight frags kt 0..5, all 16 ql (384 regs)
  short8 wreg[96];
#pragma unroll
  for (int ql = 0; ql < 16; ++ql)
#pragma unroll
    for (int kt = 0; kt < 6; ++kt)
      wreg[ql * 6 + kt] = ldg8(wsb + (ql * 8 + kt) * 512);

  // kt 6,7 staged to LDS: f = (kt-6)*16 + ql
#pragma unroll
  for (int f = 0; f < 32; ++f) {
    int kt = 6 + (f >> 4), ql = f & 15;
    short8 v = ldg8(wsb + (ql * 8 + kt) * 512);
    *reinterpret_cast<short8*>(&wlds[(w * 32 + f) * 512 + l * 8]) = v;
  }

  // zero h buffer 0 (4096 shorts)
  {
    short8 z = {0, 0, 0, 0, 0, 0, 0, 0};
    for (int i = tid; i < 512; i += NTH)
      *reinterpret_cast<short8*>(&hbuf[i * 8]) = z;
  }

  float cst[16], nst[16], mst[16];
#pragma unroll
  for (int s = 0; s < 16; ++s) { cst[s] = 0.f; nst[s] = 0.f; mst[s] = 0.f; }

  short* xp_blk = xp + (size_t)bb * TC * 16384;

  __syncthreads();

#pragma unroll 1
  for (int t0 = 0; t0 < Ss; t0 += TC) {
    // xp for next TC steps (wave-private region: no barrier needed)
    chunk_gemm4<TC>(x, WeffF, Bfrag, xp_blk, b0, w, l, t0);

#pragma unroll 1
    for (int tt = 0; tt < TC; ++tt) {
      const int t = t0 + tt, pb = t & 1;

#pragma unroll
      for (int hh = 0; hh < 4; ++hh) {
        // xp loads (consumed at gate math -> latency hidden under MFMAs)
        const short* xq = xp_blk + (size_t)tt * 16384 + (size_t)(w * 16 + hh * 4) * 256 + l * 4;
        uint2 xv[4];
#pragma unroll
        for (int g = 0; g < 4; ++g) xv[g] = *reinterpret_cast<const uint2*>(xq + g * 256);

        f32x4 acc[4];
#pragma unroll
        for (int g = 0; g < 4; ++g) acc[g] = zero4;

#pragma unroll
        for (int kt = 0; kt < 8; ++kt) {
          short8 ha = *reinterpret_cast<const short8*>(
              &hbuf[pb * 4096 + n16 * 256 + (((kt * 4 + lg) ^ n16) & 31) * 8]);
          if (kt < 6) {
#pragma unroll
            for (int g = 0; g < 4; ++g)
              acc[g] = __builtin_amdgcn_mfma_f32_16x16x32_bf16(
                  ha, wreg[(hh * 4 + g) * 6 + kt], acc[g], 0, 0, 0);
          } else {
#pragma unroll
            for (int g = 0; g < 4; ++g) {
              short8 wf = *reinterpret_cast<const short8*>(
                  &wlds[(w * 32 + (kt - 6) * 16 + hh * 4 + g) * 512 + l * 8]);
              acc[g] = __builtin_amdgcn_mfma_f32_16x16x32_bf16(ha, wf, acc[g], 0, 0, 0);
            }
          }
        }

        // gate math (deferred-max: mn = max(m, xi) >= ref's max(m+log f, xi);
        // c,n scale identically so h = sig(o)*tanh(c/n) is exactly preserved)
#pragma unroll
        for (int r = 0; r < 4; ++r) {
          const int s = hh * 4 + r;
          float xi = acc[0][r] + xvf(xv[0], r);
          float xf = acc[1][r] + xvf(xv[1], r);
          float xz = acc[2][r] + xvf(xv[2], r);
          float xo = acc[3][r] + xvf(xv[3], r);
          float mo = mst[s];
          float mn = fmaxf(mo, xi);
          float ip = __expf(xi - mn);
          float fs = frcp(1.f + __expf(-xf));      // sigmoid(xf)
          float fp = fs * __expf(mo - mn);
          float tz = tanh_fast(xz);
          float cn  = fp * cst[s] + ip * tz;
          float nn2 = fp * nst[s] + ip;
          cst[s] = cn; nst[s] = nn2; mst[s] = mn;
          float so = frcp(1.f + __expf(-xo));
          float hv = so * tanh_fast(cn * frcp(nn2));
          int j  = w * 64 + hh * 16 + n16;
          int bi = lg * 4 + r;
          hbuf[(pb ^ 1) * 4096 + bi * 256 + (((j >> 3) ^ bi) & 31) * 8 + (j & 7)] = f2bf(hv);
        }
      }
      __syncthreads();
    }
  }

  // ---------- epilogue ----------
  // final h: t=255 wrote buffer 0 (bf16) -> f32 h32 (reuses weight LDS)
  float* h32 = reinterpret_cast<float*>(smem + 16384);  // 16 x 256 f32
#pragma unroll
  for (int hh = 0; hh < 4; ++hh)
#pragma unroll
    for (int r = 0; r < 4; ++r) {
      int j = w * 64 + hh * 16 + n16, bi = lg * 4 + r;
      unsigned short u = (unsigned short)hbuf[bi * 256 + (((j >> 3) ^ bi) & 31) * 8 + (j & 7)];
      unsigned bits = (unsigned)u << 16;
      float hv;
      __builtin_memcpy(&hv, &bits, 4);
      h32[bi * 256 + j] = hv;
    }
  __syncthreads();

  float* olds = reinterpret_cast<float*>(smem + 32768);  // 16 x 24 f32
  for (int oi = tid; oi < MB * Os; oi += NTH) {
    int bi = oi / Os, o = oi % Os;
    const float* wrow = Wout + o * Hs;
    const float* hrow = h32 + bi * Hs;
    float acc = bout[o];
#pragma unroll 4
    for (int jj = 0; jj < Hs; jj += 4) {
      f32x4 hv = *(const f32x4*)(hrow + jj);
      f32x4 wv = *(const f32x4*)(wrow + jj);
      acc += hv[0] * wv[0] + hv[1] * wv[1] + hv[2] * wv[2] + hv[3] * wv[3];
    }
    olds[bi * Os + o] = acc;
  }
  __syncthreads();

  if (tid < MB) {
    float mu = 0.f;
#pragma unroll
    for (int o = 0; o < Os; ++o) mu += olds[tid * Os + o];
    mu *= (1.f / Os);
    float var = 0.f;
#pragma unroll
    for (int o = 0; o < Os; ++o) { float d = olds[tid * Os + o] - mu; var += d * d; }
    var *= (1.f / Os);
    float inv = rsqrtf(var + 1e-5f);
    for (int o = 0; o < Os; ++o)
      out[(size_t)(b0 + tid) * Os + o] = (olds[tid * Os + o] - mu) * inv;
  }
}

// ---------------- launcher ----------------
extern "C" void kernel_launch(void* const* d_in, const int* in_sizes, int n_in,
                              void* d_out, int out_size, void* d_ws, size_t ws_size,
                              hipStream_t stream) {
  const float* x    = (const float*)d_in[0];
  const float* W_in = (const float*)d_in[1];
  const float* b_in = (const float*)d_in[2];
  const float* W    = (const float*)d_in[3];
  const float* R    = (const float*)d_in[4];
  const float* bb_  = (const float*)d_in[5];
  const float* Wout = (const float*)d_in[6];
  const float* bout = (const float*)d_in[7];
  float* out = (float*)d_out;

  // workspace layout (bytes):
  //   [0, 524288)        Wst  bf16 frags
  //   [524288, 589824)   Weff bf16 frags (64 KB)
  //   [589824, 606208)   bias frags f32 (16 KB)
  //   [655360, ...)      xp packed bf16 (TC MB for 32 blocks)
  short* wst   = (short*)d_ws;
  short* weff  = (short*)((char*)d_ws + 524288);
  float* bfrag = (float*)((char*)d_ws + 589824);
  short* xp    = (short*)((char*)d_ws + 655360);

  prep_wstream<<<1024, 256, 0, stream>>>(W, R, wst);
  prep_weff<<<128, 256, 0, stream>>>(W, W_in, weff);
  prep_bfrag<<<16, 256, 0, stream>>>(W, bb_, b_in, bfrag);

  bool tc8 = ws_size >= 655360ull + 8ull * 1048576ull;
  if (tc8) {
    hipFuncSetAttribute(reinterpret_cast<const void*>(slstm_main<8>),
                        hipFuncAttributeMaxDynamicSharedMemorySize, 147456);
    slstm_main<8><<<NBLK, NTH, 147456, stream>>>(x, wst, weff, bfrag, Wout, bout, xp, out);
  } else {
    hipFuncSetAttribute(reinterpret_cast<const void*>(slstm_main<1>),
                        hipFuncAttributeMaxDynamicSharedMemorySize, 147456);
    slstm_main<1><<<NBLK, NTH, 147456, stream>>>(x, wst, weff, bfrag, Wout, bout, xp, out);
  }
}

// Round 7
// 2736.752 us; speedup vs baseline: 1.0351x; 1.0351x over previous
//
#include <hip/hip_runtime.h>
#include <hip/hip_bf16.h>

// Problem constants
constexpr int Bs = 512;   // batch
constexpr int Ss = 256;   // seq len
constexpr int Is = 32;    // input dim
constexpr int Hs = 256;   // hidden
constexpr int Os = 24;    // output dim
constexpr int MB = 16;    // batches per block
constexpr int NBLK = Bs / MB;  // 32 blocks
constexpr int NTH = 256;       // 4 waves, 1 wave/SIMD -> 512 unified regs/wave

typedef __attribute__((ext_vector_type(8))) short short8;
typedef __attribute__((ext_vector_type(4))) float f32x4;

#define DEV static __device__ __forceinline__

DEV short f2bf(float f) {
  __hip_bfloat16 h = __float2bfloat16(f);
  short s;
  __builtin_memcpy(&s, &h, 2);
  return s;
}

DEV float frcp(float x) { return __builtin_amdgcn_rcpf(x); }

DEV float tanh_fast(float x) {
  x = fminf(fmaxf(x, -15.f), 15.f);
  float u = __expf(2.f * x);
  return (u - 1.f) * frcp(u + 1.f);
}

DEV short8 ldg8(const short* p) { return *reinterpret_cast<const short8*>(p); }

DEV float xvf(uint2 v, int r) {
  unsigned wd = (r & 2) ? v.y : v.x;
  unsigned bits = ((r & 1) ? (wd >> 16) : (wd & 0xffffu)) << 16;
  float f;
  __builtin_memcpy(&f, &bits, 4);
  return f;
}

// MFMA with B operand pinned in AGPR. HAZARD CONTRACT: C input (%0) must be
// produced by a preceding MFMA (MFMA->MFMA SrcC chaining needs 0 wait states),
// and the result must next be consumed by another MFMA (builtin) so the
// compiler's hazard recognizer guards the MFMA->VALU boundary. Never place
// this first or last in the accumulation chain.
DEV f32x4 mfma_bA(short8 ha, short8 wa, f32x4 acc) {
  asm("v_mfma_f32_16x16x32_bf16 %0, %1, %2, %0" : "+v"(acc) : "v"(ha), "a"(wa));
  return acc;
}

// ---------------- prep kernels (layouts identical to verified R5) ----------------
// Frag key q = hg*4 + g, hg = hidden/16 in [0,16), g = gate (0=i,1=f,2=z,3=o).
// wst[(q*8+kt)*512 + l*8 + j] = Whr[gr][k], gr = g*256 + hg*16 + (l&15),
//   k = kt*32 + (l>>4)*8 + j, value = W[gr][256+k] + R[gr][k]
__global__ void prep_wstream(const float* __restrict__ W, const float* __restrict__ R,
                             short* __restrict__ wst) {
  int tid = blockIdx.x * 256 + threadIdx.x;  // 262144 total
  int j  = tid & 7;
  int l  = (tid >> 3) & 63;
  int kt = (tid >> 9) & 7;
  int q  = tid >> 12;          // 0..63
  int n = l & 15, kg = (l >> 4) & 3;
  int g = q & 3, hg = q >> 2;
  int gr = g * 256 + hg * 16 + n;
  int k  = kt * 32 + kg * 8 + j;
  float v = W[gr * 512 + 256 + k] + R[gr * 256 + k];
  wst[tid] = f2bf(v);
}

// Weff = Wx @ W_in (1024 x 32) as B-frags: weff[q*512 + l*8 + j]
__global__ void prep_weff(const float* __restrict__ W, const float* __restrict__ W_in,
                          short* __restrict__ weff) {
  int tid = blockIdx.x * 256 + threadIdx.x;  // 32768 total
  int j  = tid & 7;
  int l  = (tid >> 3) & 63;
  int q  = tid >> 9;           // 0..63
  int n = l & 15, kg = (l >> 4) & 3;
  int g = q & 3, hg = q >> 2;
  int gr = g * 256 + hg * 16 + n;
  int i  = kg * 8 + j;
  float acc = 0.f;
  for (int h = 0; h < Hs; ++h) acc += W[gr * 512 + h] * W_in[h * 32 + i];
  weff[tid] = f2bf(acc);
}

// bfrag[q*64 + l] = b[gr] + dot(W[gr, 0:256], b_in)
__global__ void prep_bfrag(const float* __restrict__ W, const float* __restrict__ b,
                           const float* __restrict__ b_in, float* __restrict__ bf) {
  int tid = blockIdx.x * 256 + threadIdx.x;  // 4096
  int l = tid & 63, q = tid >> 6;
  int g = q & 3, hg = q >> 2;
  int gr = g * 256 + hg * 16 + (l & 15);
  float a = b[gr];
  for (int h = 0; h < Hs; ++h) a += W[gr * 512 + h] * b_in[h];
  bf[tid] = a;
}

// ---------------- xp chunk GEMM (wave-private: wave w owns q in [w*16, w*16+16)) ----
// xps[(tt*64 + q)*256 + l*4 + r] : packed bf16, (batch=(l>>4)*4+r, col l&15 of q)
template <int TC>
DEV void chunk_gemm4(const float* __restrict__ x, const short* __restrict__ weffF,
                     const float* __restrict__ bfrag, short* __restrict__ xps,
                     int b0, int w, int l, int t0) {
  const int l15 = l & 15, lhi = l >> 4;
  short8 xa[TC];
  const float* px0 = x + (size_t)(b0 + l15) * (Ss * Is) + lhi * 8;
#pragma unroll
  for (int tt = 0; tt < TC; ++tt) {
    const float* px = px0 + (size_t)(t0 + tt) * Is;
    f32x4 a0 = *(const f32x4*)px;
    f32x4 a1 = *(const f32x4*)(px + 4);
#pragma unroll
    for (int j = 0; j < 4; ++j) { xa[tt][j] = f2bf(a0[j]); xa[tt][4 + j] = f2bf(a1[j]); }
  }
#pragma unroll
  for (int nt = 0; nt < 16; ++nt) {
    int q = w * 16 + nt;
    short8 wf = ldg8(weffF + (size_t)q * 512 + l * 8);
    float bv = bfrag[q * 64 + l];
#pragma unroll
    for (int tt = 0; tt < TC; ++tt) {
      f32x4 c = {bv, bv, bv, bv};
      c = __builtin_amdgcn_mfma_f32_16x16x32_bf16(xa[tt], wf, c, 0, 0, 0);
      unsigned lo = ((unsigned)(unsigned short)f2bf(c[1]) << 16) | (unsigned short)f2bf(c[0]);
      unsigned hi = ((unsigned)(unsigned short)f2bf(c[3]) << 16) | (unsigned short)f2bf(c[2]);
      uint2 v; v.x = lo; v.y = hi;
      *reinterpret_cast<uint2*>(xps + (size_t)tt * 16384 + (size_t)q * 256 + l * 4) = v;
    }
  }
}

// ---------------- main recurrent kernel ----------------
// 32 blocks x 4 waves (256 thr, 1 wave/SIMD -> 512 unified regs/wave).
// Wave w owns hidden [w*64, w*64+64) x 4 gates = 16 ql frags x 8 kt = 128 frags:
//   kt 0-3  -> AGPR  (64 frags = 256 acc regs, inline-asm MFMA, B-from-AGPR)
//   kt 4-5  -> VGPR  (32 frags = 128 arch regs, builtin MFMA)
//   kt 6-7  -> LDS   (32 frags/wave = 128 KB)
// MFMA issue order per acc chain: builtin(kt4,5) -> asm(kt0..3) -> builtin(kt6,7)
// so every asm MFMA's C comes from an MFMA and feeds an MFMA (hazard contract).
template <int TC>
__global__ __launch_bounds__(NTH, 1) void slstm_main(
    const float* __restrict__ x,
    const short* __restrict__ Wst,
    const short* __restrict__ WeffF,
    const float* __restrict__ Bfrag,
    const float* __restrict__ Wout,
    const float* __restrict__ bout,
    short* __restrict__ xp,
    float* __restrict__ out)
{
  extern __shared__ char smem[];
  short* hbuf = reinterpret_cast<short*>(smem);            // 2 * 4096 shorts = 16 KB
  short* wlds = reinterpret_cast<short*>(smem + 16384);    // 4*32*512 shorts = 128 KB

  const int tid = threadIdx.x;
  const int w   = tid >> 6;   // 0..3
  const int l   = tid & 63;
  const int lg  = l >> 4;
  const int n16 = l & 15;
  const int bb  = blockIdx.x;
  const int b0  = bb * MB;

  const short* wsb = Wst + (size_t)(w * 16 * 8) * 512 + l * 8;  // frag(ql,kt) at +(ql*8+kt)*512
  const f32x4 zero4 = {0.f, 0.f, 0.f, 0.f};

  // AGPR-pinned frags kt 0..3 (indexed [ql][kt], compile-time only)
  short8 wa[16][4];
#pragma unroll
  for (int ql = 0; ql < 16; ++ql)
#pragma unroll
    for (int kt = 0; kt < 4; ++kt)
      wa[ql][kt] = ldg8(wsb + (ql * 8 + kt) * 512);

  // VGPR frags kt 4..5
  short8 wv[16][2];
#pragma unroll
  for (int ql = 0; ql < 16; ++ql)
#pragma unroll
    for (int kt = 0; kt < 2; ++kt)
      wv[ql][kt] = ldg8(wsb + (ql * 8 + 4 + kt) * 512);

  // kt 6,7 staged to LDS: offset ((w*2 + (kt-6))*16 + ql)*512
#pragma unroll
  for (int f = 0; f < 32; ++f) {
    int kt = f >> 4, ql = f & 15;
    short8 v = ldg8(wsb + (ql * 8 + 6 + kt) * 512);
    *reinterpret_cast<short8*>(&wlds[((w * 2 + kt) * 16 + ql) * 512 + l * 8]) = v;
  }

  // zero h buffer 0 (4096 shorts)
  {
    short8 z = {0, 0, 0, 0, 0, 0, 0, 0};
    for (int i = tid; i < 512; i += NTH)
      *reinterpret_cast<short8*>(&hbuf[i * 8]) = z;
  }

  float cst[16], nst[16], mst[16];
#pragma unroll
  for (int s = 0; s < 16; ++s) { cst[s] = 0.f; nst[s] = 0.f; mst[s] = 0.f; }

  short* xp_blk = xp + (size_t)bb * TC * 16384;

  __syncthreads();

#pragma unroll 1
  for (int t0 = 0; t0 < Ss; t0 += TC) {
    // xp for next TC steps (wave-private region: no barrier needed)
    chunk_gemm4<TC>(x, WeffF, Bfrag, xp_blk, b0, w, l, t0);

#pragma unroll 1
    for (int tt = 0; tt < TC; ++tt) {
      const int t = t0 + tt, pb = t & 1;

#pragma unroll
      for (int hh = 0; hh < 4; ++hh) {
        // xp loads (consumed at gate math -> latency hidden under MFMAs)
        const short* xq = xp_blk + (size_t)tt * 16384 + (size_t)(w * 16 + hh * 4) * 256 + l * 4;
        uint2 xv[4];
#pragma unroll
        for (int g = 0; g < 4; ++g) xv[g] = *reinterpret_cast<const uint2*>(xq + g * 256);

        // h A-frags for each kt chunk (from swizzled LDS dbuf)
        f32x4 acc[4];

        // ---- section 1: kt 4,5 (builtin, VGPR) — consumes VALU zero-init ----
        {
          short8 ha4 = *reinterpret_cast<const short8*>(
              &hbuf[pb * 4096 + n16 * 256 + (((4 * 4 + lg) ^ n16) & 31) * 8]);
          short8 ha5 = *reinterpret_cast<const short8*>(
              &hbuf[pb * 4096 + n16 * 256 + (((5 * 4 + lg) ^ n16) & 31) * 8]);
#pragma unroll
          for (int g = 0; g < 4; ++g)
            acc[g] = __builtin_amdgcn_mfma_f32_16x16x32_bf16(
                ha4, wv[hh * 4 + g][0], zero4, 0, 0, 0);
#pragma unroll
          for (int g = 0; g < 4; ++g)
            acc[g] = __builtin_amdgcn_mfma_f32_16x16x32_bf16(
                ha5, wv[hh * 4 + g][1], acc[g], 0, 0, 0);
        }

        // ---- section 2: kt 0..3 (asm, AGPR) — C chained from MFMA ----
#pragma unroll
        for (int kt = 0; kt < 4; ++kt) {
          short8 ha = *reinterpret_cast<const short8*>(
              &hbuf[pb * 4096 + n16 * 256 + (((kt * 4 + lg) ^ n16) & 31) * 8]);
#pragma unroll
          for (int g = 0; g < 4; ++g)
            acc[g] = mfma_bA(ha, wa[hh * 4 + g][kt], acc[g]);
        }

        // ---- section 3: kt 6,7 (builtin, LDS) — final writes are builtin ----
#pragma unroll
        for (int kt = 6; kt < 8; ++kt) {
          short8 ha = *reinterpret_cast<const short8*>(
              &hbuf[pb * 4096 + n16 * 256 + (((kt * 4 + lg) ^ n16) & 31) * 8]);
#pragma unroll
          for (int g = 0; g < 4; ++g) {
            short8 wf = *reinterpret_cast<const short8*>(
                &wlds[((w * 2 + (kt - 6)) * 16 + hh * 4 + g) * 512 + l * 8]);
            acc[g] = __builtin_amdgcn_mfma_f32_16x16x32_bf16(ha, wf, acc[g], 0, 0, 0);
          }
        }

        // gate math (deferred-max: mn = max(m, xi) >= ref's max(m+log f, xi);
        // c,n scale identically so h = sig(o)*tanh(c/n) is exactly preserved)
#pragma unroll
        for (int r = 0; r < 4; ++r) {
          const int s = hh * 4 + r;
          float xi = acc[0][r] + xvf(xv[0], r);
          float xf = acc[1][r] + xvf(xv[1], r);
          float xz = acc[2][r] + xvf(xv[2], r);
          float xo = acc[3][r] + xvf(xv[3], r);
          float mo = mst[s];
          float mn = fmaxf(mo, xi);
          float ip = __expf(xi - mn);
          float fs = frcp(1.f + __expf(-xf));      // sigmoid(xf)
          float fp = fs * __expf(mo - mn);
          float tz = tanh_fast(xz);
          float cn  = fp * cst[s] + ip * tz;
          float nn2 = fp * nst[s] + ip;
          cst[s] = cn; nst[s] = nn2; mst[s] = mn;
          float so = frcp(1.f + __expf(-xo));
          float hv = so * tanh_fast(cn * frcp(nn2));
          int j  = w * 64 + hh * 16 + n16;
          int bi = lg * 4 + r;
          hbuf[(pb ^ 1) * 4096 + bi * 256 + (((j >> 3) ^ bi) & 31) * 8 + (j & 7)] = f2bf(hv);
        }
      }
      __syncthreads();
    }
  }

  // ---------- epilogue ----------
  // final h: t=255 wrote buffer 0 (bf16) -> f32 h32 (reuses weight LDS)
  float* h32 = reinterpret_cast<float*>(smem + 16384);  // 16 x 256 f32
#pragma unroll
  for (int hh = 0; hh < 4; ++hh)
#pragma unroll
    for (int r = 0; r < 4; ++r) {
      int j = w * 64 + hh * 16 + n16, bi = lg * 4 + r;
      unsigned short u = (unsigned short)hbuf[bi * 256 + (((j >> 3) ^ bi) & 31) * 8 + (j & 7)];
      unsigned bits = (unsigned)u << 16;
      float hv;
      __builtin_memcpy(&hv, &bits, 4);
      h32[bi * 256 + j] = hv;
    }
  __syncthreads();

  float* olds = reinterpret_cast<float*>(smem + 32768);  // 16 x 24 f32
  for (int oi = tid; oi < MB * Os; oi += NTH) {
    int bi = oi / Os, o = oi % Os;
    const float* wrow = Wout + o * Hs;
    const float* hrow = h32 + bi * Hs;
    float acc = bout[o];
#pragma unroll 4
    for (int jj = 0; jj < Hs; jj += 4) {
      f32x4 hv = *(const f32x4*)(hrow + jj);
      f32x4 wv2 = *(const f32x4*)(wrow + jj);
      acc += hv[0] * wv2[0] + hv[1] * wv2[1] + hv[2] * wv2[2] + hv[3] * wv2[3];
    }
    olds[bi * Os + o] = acc;
  }
  __syncthreads();

  if (tid < MB) {
    float mu = 0.f;
#pragma unroll
    for (int o = 0; o < Os; ++o) mu += olds[tid * Os + o];
    mu *= (1.f / Os);
    float var = 0.f;
#pragma unroll
    for (int o = 0; o < Os; ++o) { float d = olds[tid * Os + o] - mu; var += d * d; }
    var *= (1.f / Os);
    float inv = rsqrtf(var + 1e-5f);
    for (int o = 0; o < Os; ++o)
      out[(size_t)(b0 + tid) * Os + o] = (olds[tid * Os + o] - mu) * inv;
  }
}

// ---------------- launcher ----------------
extern "C" void kernel_launch(void* const* d_in, const int* in_sizes, int n_in,
                              void* d_out, int out_size, void* d_ws, size_t ws_size,
                              hipStream_t stream) {
  const float* x    = (const float*)d_in[0];
  const float* W_in = (const float*)d_in[1];
  const float* b_in = (const float*)d_in[2];
  const float* W    = (const float*)d_in[3];
  const float* R    = (const float*)d_in[4];
  const float* bb_  = (const float*)d_in[5];
  const float* Wout = (const float*)d_in[6];
  const float* bout = (const float*)d_in[7];
  float* out = (float*)d_out;

  // workspace layout (bytes):
  //   [0, 524288)        Wst  bf16 frags
  //   [524288, 589824)   Weff bf16 frags (64 KB)
  //   [589824, 606208)   bias frags f32 (16 KB)
  //   [655360, ...)      xp packed bf16 (TC MB for 32 blocks)
  short* wst   = (short*)d_ws;
  short* weff  = (short*)((char*)d_ws + 524288);
  float* bfrag = (float*)((char*)d_ws + 589824);
  short* xp    = (short*)((char*)d_ws + 655360);

  prep_wstream<<<1024, 256, 0, stream>>>(W, R, wst);
  prep_weff<<<128, 256, 0, stream>>>(W, W_in, weff);
  prep_bfrag<<<16, 256, 0, stream>>>(W, bb_, b_in, bfrag);

  bool tc8 = ws_size >= 655360ull + 8ull * 1048576ull;
  if (tc8) {
    hipFuncSetAttribute(reinterpret_cast<const void*>(slstm_main<8>),
                        hipFuncAttributeMaxDynamicSharedMemorySize, 147456);
    slstm_main<8><<<NBLK, NTH, 147456, stream>>>(x, wst, weff, bfrag, Wout, bout, xp, out);
  } else {
    hipFuncSetAttribute(reinterpret_cast<const void*>(slstm_main<1>),
                        hipFuncAttributeMaxDynamicSharedMemorySize, 147456);
    slstm_main<1><<<NBLK, NTH, 147456, stream>>>(x, wst, weff, bfrag, Wout, bout, xp, out);
  }
}

// Round 8
// 1839.097 us; speedup vs baseline: 1.5404x; 1.4881x over previous
//
#include <hip/hip_runtime.h>
#include <hip/hip_bf16.h>

// Problem constants
constexpr int Bs = 512;   // batch
constexpr int Ss = 256;   // seq len
constexpr int Is = 32;    // input dim
constexpr int Hs = 256;   // hidden
constexpr int Os = 24;    // output dim
constexpr int MB = 16;    // batches per block
constexpr int NBLK = Bs / MB;  // 32 blocks
constexpr int NTH = 512;       // 8 waves, 2 waves/SIMD -> 256 regs/wave

typedef __attribute__((ext_vector_type(8))) short short8;
typedef __attribute__((ext_vector_type(4))) float f32x4;

#define DEV static __device__ __forceinline__

DEV short f2bf(float f) {
  __hip_bfloat16 h = __float2bfloat16(f);
  short s;
  __builtin_memcpy(&s, &h, 2);
  return s;
}

DEV float frcp(float x) { return __builtin_amdgcn_rcpf(x); }

DEV float tanh_fast(float x) {
  x = fminf(fmaxf(x, -15.f), 15.f);
  float u = __expf(2.f * x);
  return (u - 1.f) * frcp(u + 1.f);
}

DEV short8 ldg8(const short* p) { return *reinterpret_cast<const short8*>(p); }

DEV float xvf(uint2 v, int r) {
  unsigned wd = (r & 2) ? v.y : v.x;
  unsigned bits = ((r & 1) ? (wd >> 16) : (wd & 0xffffu)) << 16;
  float f;
  __builtin_memcpy(&f, &bits, 4);
  return f;
}

// ---------------- prep kernels (layouts identical to verified R5/R7) ------------
// Frag key q = hg*4 + g, hg = hidden/16 in [0,16), g = gate (0=i,1=f,2=z,3=o).
// wst[(q*8+kt)*512 + l*8 + j] = Whr[gr][k], gr = g*256 + hg*16 + (l&15),
//   k = kt*32 + (l>>4)*8 + j, value = W[gr][256+k] + R[gr][k]
__global__ void prep_wstream(const float* __restrict__ W, const float* __restrict__ R,
                             short* __restrict__ wst) {
  int tid = blockIdx.x * 256 + threadIdx.x;  // 262144 total
  int j  = tid & 7;
  int l  = (tid >> 3) & 63;
  int kt = (tid >> 9) & 7;
  int q  = tid >> 12;          // 0..63
  int n = l & 15, kg = (l >> 4) & 3;
  int g = q & 3, hg = q >> 2;
  int gr = g * 256 + hg * 16 + n;
  int k  = kt * 32 + kg * 8 + j;
  float v = W[gr * 512 + 256 + k] + R[gr * 256 + k];
  wst[tid] = f2bf(v);
}

// Weff = Wx @ W_in (1024 x 32) as B-frags: weff[q*512 + l*8 + j]
__global__ void prep_weff(const float* __restrict__ W, const float* __restrict__ W_in,
                          short* __restrict__ weff) {
  int tid = blockIdx.x * 256 + threadIdx.x;  // 32768 total
  int j  = tid & 7;
  int l  = (tid >> 3) & 63;
  int q  = tid >> 9;           // 0..63
  int n = l & 15, kg = (l >> 4) & 3;
  int g = q & 3, hg = q >> 2;
  int gr = g * 256 + hg * 16 + n;
  int i  = kg * 8 + j;
  float acc = 0.f;
  for (int h = 0; h < Hs; ++h) acc += W[gr * 512 + h] * W_in[h * 32 + i];
  weff[tid] = f2bf(acc);
}

// bfrag[q*64 + l] = b[gr] + dot(W[gr, 0:256], b_in)
__global__ void prep_bfrag(const float* __restrict__ W, const float* __restrict__ b,
                           const float* __restrict__ b_in, float* __restrict__ bf) {
  int tid = blockIdx.x * 256 + threadIdx.x;  // 4096
  int l = tid & 63, q = tid >> 6;
  int g = q & 3, hg = q >> 2;
  int gr = g * 256 + hg * 16 + (l & 15);
  float a = b[gr];
  for (int h = 0; h < Hs; ++h) a += W[gr * 512 + h] * b_in[h];
  bf[tid] = a;
}

// ---------------- xp chunk GEMM (wave-private: wave w owns q in [w*8, w*8+8)) ----
// xps[(tt*64 + q)*256 + l*4 + r] : packed bf16, (batch=(l>>4)*4+r, col l&15 of q)
template <int TC>
DEV void chunk_gemm8(const float* __restrict__ x, const short* __restrict__ weffF,
                     const float* __restrict__ bfrag, short* __restrict__ xps,
                     int b0, int w, int l, int t0) {
  const int l15 = l & 15, lhi = l >> 4;
  short8 xa[TC];
  const float* px0 = x + (size_t)(b0 + l15) * (Ss * Is) + lhi * 8;
#pragma unroll
  for (int tt = 0; tt < TC; ++tt) {
    const float* px = px0 + (size_t)(t0 + tt) * Is;
    f32x4 a0 = *(const f32x4*)px;
    f32x4 a1 = *(const f32x4*)(px + 4);
#pragma unroll
    for (int j = 0; j < 4; ++j) { xa[tt][j] = f2bf(a0[j]); xa[tt][4 + j] = f2bf(a1[j]); }
  }
#pragma unroll
  for (int nt = 0; nt < 8; ++nt) {
    int q = w * 8 + nt;
    short8 wf = ldg8(weffF + (size_t)q * 512 + l * 8);
    float bv = bfrag[q * 64 + l];
#pragma unroll
    for (int tt = 0; tt < TC; ++tt) {
      f32x4 c = {bv, bv, bv, bv};
      c = __builtin_amdgcn_mfma_f32_16x16x32_bf16(xa[tt], wf, c, 0, 0, 0);
      unsigned lo = ((unsigned)(unsigned short)f2bf(c[1]) << 16) | (unsigned short)f2bf(c[0]);
      unsigned hi = ((unsigned)(unsigned short)f2bf(c[3]) << 16) | (unsigned short)f2bf(c[2]);
      uint2 v; v.x = lo; v.y = hi;
      *reinterpret_cast<uint2*>(xps + (size_t)tt * 16384 + (size_t)q * 256 + l * 4) = v;
    }
  }
}

// ---------------- main recurrent kernel ----------------
// 32 blocks x 8 waves (2 waves/SIMD for TLP). Wave w owns q in [w*8, w*8+8)
// (= hidden [w*32,w*32+32) x 4 gates), 8 kt each. Weight delivery per step,
// sized to tier bandwidth (parallel pipes):
//   kt 0-2 -> registers (24 frags = 96 regs, loaded once)
//   kt 3-4 -> LDS       (16 frags/wave = 128 KB total, LDS port)
//   kt 5-7 -> streamed from L2 each step (192 KB/CU/step, ~64 B/cy port)
// Named stream buffers (no pointer-selected arrays -> no scratch). Memory
// clobber per step prevents hoisting streamed loads into phantom residency.
template <int TC>
__global__ __launch_bounds__(NTH, 2) void slstm_main(
    const float* __restrict__ x,
    const short* __restrict__ Wst,
    const short* __restrict__ WeffF,
    const float* __restrict__ Bfrag,
    const float* __restrict__ Wout,
    const float* __restrict__ bout,
    short* __restrict__ xp,
    float* __restrict__ out)
{
  extern __shared__ char smem[];
  short* hbuf = reinterpret_cast<short*>(smem);            // 2 * 4096 shorts = 16 KB
  short* wlds = reinterpret_cast<short*>(smem + 16384);    // 8*16*512 shorts = 128 KB

  const int tid = threadIdx.x;
  const int w   = tid >> 6;   // 0..7
  const int l   = tid & 63;
  const int lg  = l >> 4;
  const int n16 = l & 15;
  const int bb  = blockIdx.x;
  const int b0  = bb * MB;

  const short* wsb = Wst + (size_t)(w * 8 * 8) * 512 + l * 8;  // frag(nt,kt) at +(nt*8+kt)*512
  const f32x4 zero4 = {0.f, 0.f, 0.f, 0.f};

  // resident weight frags kt 0..2 (24 frags = 96 regs)
  short8 wreg[24];
#pragma unroll
  for (int nt = 0; nt < 8; ++nt)
#pragma unroll
    for (int kt = 0; kt < 3; ++kt)
      wreg[nt * 3 + kt] = ldg8(wsb + (nt * 8 + kt) * 512);

  // kt 3,4 staged to LDS: offset ((w*2 + (kt-3))*8 + nt)*512
#pragma unroll
  for (int f = 0; f < 16; ++f) {
    int kt = f >> 3, nt = f & 7;
    short8 v = ldg8(wsb + (nt * 8 + 3 + kt) * 512);
    *reinterpret_cast<short8*>(&wlds[((w * 2 + kt) * 8 + nt) * 512 + l * 8]) = v;
  }

  // zero h buffer 0 (4096 shorts; 512 threads x 1 short8)
  {
    short8 z = {0, 0, 0, 0, 0, 0, 0, 0};
    *reinterpret_cast<short8*>(&hbuf[tid * 8]) = z;
  }

  float cst[8], nst[8], mst[8];
#pragma unroll
  for (int s = 0; s < 8; ++s) { cst[s] = 0.f; nst[s] = 0.f; mst[s] = 0.f; }

  short* xp_blk = xp + (size_t)bb * TC * 16384;

  __syncthreads();

#pragma unroll 1
  for (int t0 = 0; t0 < Ss; t0 += TC) {
    // xp for next TC steps (wave-private region: no barrier needed)
    chunk_gemm8<TC>(x, WeffF, Bfrag, xp_blk, b0, w, l, t0);

#pragma unroll 1
    for (int tt = 0; tt < TC; ++tt) {
      const int t = t0 + tt, pb = t & 1;
      // force streamed weight loads to re-issue each step (values in wreg
      // registers are unaffected; only memory re-reads are forced)
      asm volatile("" ::: "memory");

      // stream kt5 -> bufA (issued first: full-step latency cover)
      short8 bufA[8];
#pragma unroll
      for (int nt = 0; nt < 8; ++nt) bufA[nt] = ldg8(wsb + (nt * 8 + 5) * 512);

      // xp loads (consumed only at gate math)
      uint2 xv[8];
#pragma unroll
      for (int nt = 0; nt < 8; ++nt)
        xv[nt] = *reinterpret_cast<const uint2*>(
            xp_blk + (size_t)tt * 16384 + (size_t)(w * 8 + nt) * 256 + l * 4);

      f32x4 acc[8];

      // ---- kt 0..2 from registers ----
#pragma unroll
      for (int kt = 0; kt < 3; ++kt) {
        short8 ha = *reinterpret_cast<const short8*>(
            &hbuf[pb * 4096 + n16 * 256 + (((kt * 4 + lg) ^ n16) & 31) * 8]);
        if (kt == 0) {
#pragma unroll
          for (int nt = 0; nt < 8; ++nt)
            acc[nt] = __builtin_amdgcn_mfma_f32_16x16x32_bf16(ha, wreg[nt * 3], zero4, 0, 0, 0);
        } else {
#pragma unroll
          for (int nt = 0; nt < 8; ++nt)
            acc[nt] = __builtin_amdgcn_mfma_f32_16x16x32_bf16(ha, wreg[nt * 3 + kt], acc[nt], 0, 0, 0);
        }
      }

      // stream kt6 -> bufB
      short8 bufB[8];
#pragma unroll
      for (int nt = 0; nt < 8; ++nt) bufB[nt] = ldg8(wsb + (nt * 8 + 6) * 512);

      // ---- kt 3,4 from LDS ----
#pragma unroll
      for (int kt = 3; kt < 5; ++kt) {
        short8 ha = *reinterpret_cast<const short8*>(
            &hbuf[pb * 4096 + n16 * 256 + (((kt * 4 + lg) ^ n16) & 31) * 8]);
#pragma unroll
        for (int nt = 0; nt < 8; ++nt) {
          short8 wf = *reinterpret_cast<const short8*>(
              &wlds[((w * 2 + (kt - 3)) * 8 + nt) * 512 + l * 8]);
          acc[nt] = __builtin_amdgcn_mfma_f32_16x16x32_bf16(ha, wf, acc[nt], 0, 0, 0);
        }
      }

      // ---- kt 5 from bufA ----
      {
        short8 ha = *reinterpret_cast<const short8*>(
            &hbuf[pb * 4096 + n16 * 256 + (((5 * 4 + lg) ^ n16) & 31) * 8]);
#pragma unroll
        for (int nt = 0; nt < 8; ++nt)
          acc[nt] = __builtin_amdgcn_mfma_f32_16x16x32_bf16(ha, bufA[nt], acc[nt], 0, 0, 0);
      }

      // stream kt7 -> bufC
      short8 bufC[8];
#pragma unroll
      for (int nt = 0; nt < 8; ++nt) bufC[nt] = ldg8(wsb + (nt * 8 + 7) * 512);

      // ---- kt 6 from bufB ----
      {
        short8 ha = *reinterpret_cast<const short8*>(
            &hbuf[pb * 4096 + n16 * 256 + (((6 * 4 + lg) ^ n16) & 31) * 8]);
#pragma unroll
        for (int nt = 0; nt < 8; ++nt)
          acc[nt] = __builtin_amdgcn_mfma_f32_16x16x32_bf16(ha, bufB[nt], acc[nt], 0, 0, 0);
      }
      // ---- kt 7 from bufC ----
      {
        short8 ha = *reinterpret_cast<const short8*>(
            &hbuf[pb * 4096 + n16 * 256 + (((7 * 4 + lg) ^ n16) & 31) * 8]);
#pragma unroll
        for (int nt = 0; nt < 8; ++nt)
          acc[nt] = __builtin_amdgcn_mfma_f32_16x16x32_bf16(ha, bufC[nt], acc[nt], 0, 0, 0);
      }

      // gate math (deferred-max, verified R5/R7) + h write to other buffer
#pragma unroll
      for (int hgl = 0; hgl < 2; ++hgl) {
#pragma unroll
        for (int r = 0; r < 4; ++r) {
          const int s = hgl * 4 + r;
          float xi = acc[hgl * 4 + 0][r] + xvf(xv[hgl * 4 + 0], r);
          float xf = acc[hgl * 4 + 1][r] + xvf(xv[hgl * 4 + 1], r);
          float xz = acc[hgl * 4 + 2][r] + xvf(xv[hgl * 4 + 2], r);
          float xo = acc[hgl * 4 + 3][r] + xvf(xv[hgl * 4 + 3], r);
          float mo = mst[s];
          float mn = fmaxf(mo, xi);
          float ip = __expf(xi - mn);
          float fs = frcp(1.f + __expf(-xf));      // sigmoid(xf)
          float fp = fs * __expf(mo - mn);
          float tz = tanh_fast(xz);
          float cn  = fp * cst[s] + ip * tz;
          float nn2 = fp * nst[s] + ip;
          cst[s] = cn; nst[s] = nn2; mst[s] = mn;
          float so = frcp(1.f + __expf(-xo));
          float hv = so * tanh_fast(cn * frcp(nn2));
          int j  = w * 32 + hgl * 16 + n16;
          int bi = lg * 4 + r;
          hbuf[(pb ^ 1) * 4096 + bi * 256 + (((j >> 3) ^ bi) & 31) * 8 + (j & 7)] = f2bf(hv);
        }
      }
      __syncthreads();
    }
  }

  // ---------- epilogue (verified R3 8-wave form) ----------
  float* h32 = reinterpret_cast<float*>(smem + 16384);  // 16 x 256 f32
#pragma unroll
  for (int hgl = 0; hgl < 2; ++hgl)
#pragma unroll
    for (int r = 0; r < 4; ++r) {
      int j = w * 32 + hgl * 16 + n16, bi = lg * 4 + r;
      unsigned short u = (unsigned short)hbuf[bi * 256 + (((j >> 3) ^ bi) & 31) * 8 + (j & 7)];
      unsigned bits = (unsigned)u << 16;
      float hv;
      __builtin_memcpy(&hv, &bits, 4);
      h32[bi * 256 + j] = hv;
    }
  __syncthreads();

  float* olds = reinterpret_cast<float*>(smem + 32768);  // 16 x 24 f32
  if (tid < MB * Os) {
    int bi = tid / Os, o = tid % Os;
    const float* wrow = Wout + o * Hs;
    const float* hrow = h32 + bi * Hs;
    float acc = bout[o];
#pragma unroll 4
    for (int jj = 0; jj < Hs; jj += 4) {
      f32x4 hv = *(const f32x4*)(hrow + jj);
      f32x4 wv = *(const f32x4*)(wrow + jj);
      acc += hv[0] * wv[0] + hv[1] * wv[1] + hv[2] * wv[2] + hv[3] * wv[3];
    }
    olds[bi * Os + o] = acc;
  }
  __syncthreads();

  if (tid < MB) {
    float mu = 0.f;
#pragma unroll
    for (int o = 0; o < Os; ++o) mu += olds[tid * Os + o];
    mu *= (1.f / Os);
    float var = 0.f;
#pragma unroll
    for (int o = 0; o < Os; ++o) { float d = olds[tid * Os + o] - mu; var += d * d; }
    var *= (1.f / Os);
    float inv = rsqrtf(var + 1e-5f);
    for (int o = 0; o < Os; ++o)
      out[(size_t)(b0 + tid) * Os + o] = (olds[tid * Os + o] - mu) * inv;
  }
}

// ---------------- launcher ----------------
extern "C" void kernel_launch(void* const* d_in, const int* in_sizes, int n_in,
                              void* d_out, int out_size, void* d_ws, size_t ws_size,
                              hipStream_t stream) {
  const float* x    = (const float*)d_in[0];
  const float* W_in = (const float*)d_in[1];
  const float* b_in = (const float*)d_in[2];
  const float* W    = (const float*)d_in[3];
  const float* R    = (const float*)d_in[4];
  const float* bb_  = (const float*)d_in[5];
  const float* Wout = (const float*)d_in[6];
  const float* bout = (const float*)d_in[7];
  float* out = (float*)d_out;

  // workspace layout (bytes):
  //   [0, 524288)        Wst  bf16 frags
  //   [524288, 589824)   Weff bf16 frags (64 KB)
  //   [589824, 606208)   bias frags f32 (16 KB)
  //   [655360, ...)      xp packed bf16 (TC MB for 32 blocks)
  short* wst   = (short*)d_ws;
  short* weff  = (short*)((char*)d_ws + 524288);
  float* bfrag = (float*)((char*)d_ws + 589824);
  short* xp    = (short*)((char*)d_ws + 655360);

  prep_wstream<<<1024, 256, 0, stream>>>(W, R, wst);
  prep_weff<<<128, 256, 0, stream>>>(W, W_in, weff);
  prep_bfrag<<<16, 256, 0, stream>>>(W, bb_, b_in, bfrag);

  bool tc8 = ws_size >= 655360ull + 8ull * 1048576ull;
  if (tc8) {
    hipFuncSetAttribute(reinterpret_cast<const void*>(slstm_main<8>),
                        hipFuncAttributeMaxDynamicSharedMemorySize, 147456);
    slstm_main<8><<<NBLK, NTH, 147456, stream>>>(x, wst, weff, bfrag, Wout, bout, xp, out);
  } else {
    hipFuncSetAttribute(reinterpret_cast<const void*>(slstm_main<1>),
                        hipFuncAttributeMaxDynamicSharedMemorySize, 147456);
    slstm_main<1><<<NBLK, NTH, 147456, stream>>>(x, wst, weff, bfrag, Wout, bout, xp, out);
  }
}